// Round 22
// baseline (688.051 us; speedup 1.0000x reference)
//
#include <hip/hip_runtime.h>

// KNN top-16: B=4, N=M=8192, C=3.  (GOLD METRIC LOCKED by R17, absmax=0:
//   norms = (x²+z²)+y² [hsum, plain]; cross = fma(z,z',fma(y,y',x*x'));
//   d2 = max((q2+r2) - 2*cross, 0); stable (d2,idx) ascending; 0-based.)
// R22: LDS-reuse attack. Each thread serves TWO queries (A=slot, B=slot+32)
// on the same ref subset: one ds_read_b128 feeds 2 evals (halves the
// ~12cyc/b128 LDS-pipe cost/eval). Metric packed 2-wide (v_pk_fma_f32,
// per-element IEEE == scalar gold chain). SINGLE queue: append u16 loc when
// min(d2A,d2B) <= max(TA,TB) (conservative); compact recomputes both exact
// scalar metrics from the live tile and inserts into each top-16.
// Shape: TPB=256, QPB=64, SPL=8, grid 512 = 2 blk/CU x 8 waves = 16 w/CU.

#define TPB 256
#define QPB 64   // queries per block (32 A + 32 B)
#define SPL 8    // threads per query
#define KK 16
#define TILE_PTS 512
#define CAP 24   // queue slots per thread (7 + 2*8 = 23 <= 24)
#define TRIG 8   // compaction trigger (checked every 8 points)

typedef float v2f __attribute__((ext_vector_type(2)));

__global__ __launch_bounds__(TPB, 2) void knn_topk_kernel(
    const float* __restrict__ ref, const float* __restrict__ query,
    float* __restrict__ dout, float* __restrict__ iout, int N, int M) {
#pragma clang fp contract(off)
  __shared__ float4 tile[TILE_PTS];              // 8 KB: x,y,z,r2 (HSUM)
  __shared__ unsigned short si[CAP * TPB];       // 12 KB: queue (local idx)
  __shared__ float md[KK * TPB];                 // 16 KB: merge staging

  const int tid = threadIdx.x;
  const int h = tid & (SPL - 1);
  const int qidA = blockIdx.x * QPB + (tid >> 3);
  const int qidB = qidA + 32;                    // same batch (8192%64==0)
  const int b = qidA / M;

  const float* qpA = query + (size_t)qidA * 3;
  const float* qpB = query + (size_t)qidB * 3;
  const float qxA = qpA[0], qyA = qpA[1], qzA = qpA[2];
  const float qxB = qpB[0], qyB = qpB[1], qzB = qpB[2];
  const float q2A = (qxA * qxA + qzA * qzA) + qyA * qyA;  // HSUM norm
  const float q2B = (qxB * qxB + qzB * qzB) + qyB * qyB;
  const v2f qxv = {qxA, qxB}, qyv = {qyA, qyB}, qzv = {qzA, qzB};
  const v2f q2v = {q2A, q2B};
  const v2f m2v = {-2.0f, -2.0f};

  float aA[KK], aB[KK];
  int aiA[KK], aiB[KK];
#pragma unroll
  for (int s = 0; s < KK; ++s) {
    aA[s] = 3.0e38f; aiA[s] = 0; aB[s] = 3.0e38f; aiB[s] = 0;
  }
  float TA = 3.0e38f, TB = 3.0e38f;  // per-query shared screens (8-lane min)
  float Tmax = 3.0e38f;              // max(TA,TB): single screen compare
  int cnt = 0;

  const float* refb = ref + (size_t)b * N * 3;

  auto ins = [&](float (&a)[KK], int (&ai)[KK], float d, int ix) {
    bool pc = false;
    float pa = 0.f;
    int pi = 0;
#pragma unroll
    for (int s = 0; s < KK; ++s) {
      float oa = a[s];
      int oi = ai[s];
      bool c = d < oa;  // strict: stable (after equals)
      a[s] = c ? (pc ? pa : d) : oa;
      ai[s] = c ? (pc ? pi : ix) : oi;
      pc = c;
      pa = oa;
      pi = oi;
    }
  };

  // Exact scalar recompute for BOTH queries + inserts + refresh screens.
  // Wave-uniform call sites only (shuffles inside).
  auto compact = [&](int tbase) {
    int cm = cnt;
    for (int s = 0; s < cm; ++s) {
      int loc = si[s * TPB + tid];
      float4 p = tile[loc];
      float crA = qxA * p.x;
      crA = __builtin_fmaf(qyA, p.y, crA);
      crA = __builtin_fmaf(qzA, p.z, crA);
      float d2A = __builtin_fmaf(-2.0f, crA, q2A + p.w);
      float dA = d2A < 0.f ? 0.f : d2A;
      if (dA < aA[KK - 1]) ins(aA, aiA, dA, tbase + loc);
      float crB = qxB * p.x;
      crB = __builtin_fmaf(qyB, p.y, crB);
      crB = __builtin_fmaf(qzB, p.z, crB);
      float d2B = __builtin_fmaf(-2.0f, crB, q2B + p.w);
      float dB = d2B < 0.f ? 0.f : d2B;
      if (dB < aB[KK - 1]) ins(aB, aiB, dB, tbase + loc);
    }
    cnt = 0;
    float mA = aA[KK - 1], mB = aB[KK - 1];
    mA = fminf(mA, __shfl_xor(mA, 1));
    mA = fminf(mA, __shfl_xor(mA, 2));
    TA = fminf(mA, __shfl_xor(mA, 4));
    mB = fminf(mB, __shfl_xor(mB, 1));
    mB = fminf(mB, __shfl_xor(mB, 2));
    TB = fminf(mB, __shfl_xor(mB, 4));
    Tmax = fmaxf(TA, TB);
  };

  const int ntiles = N / TILE_PTS;
  for (int t = 0; t < ntiles; ++t) {
    __syncthreads();
    {
      // Stage 512 points; w = HSUM norm (x2+z2)+y2.
      int pl = tid * 2;
      const float* rp = refb + (size_t)(t * TILE_PTS + pl) * 3;
#pragma unroll
      for (int u = 0; u < 2; ++u) {
        float rx = rp[3 * u + 0];
        float ry = rp[3 * u + 1];
        float rz = rp[3 * u + 2];
        float r2 = (rx * rx + rz * rz) + ry * ry;
        tile[pl + u] = make_float4(rx, ry, rz, r2);
      }
    }
    __syncthreads();
    const int tbase = t * TILE_PTS;
    for (int g = 0; g < TILE_PTS / SPL; g += 8) {
#pragma unroll
      for (int u = 0; u < 8; ++u) {
        const int loc = (g + u) * SPL + h;  // subset h: refs ≡ h (mod 8)
        float4 p = tile[loc];               // one b128, 2 evals
        // Packed 2-query metric (per-element == scalar gold chain):
        v2f cr = qxv * p.x;
        cr = __builtin_elementwise_fma(qyv, (v2f){p.y, p.y}, cr);
        cr = __builtin_elementwise_fma(qzv, (v2f){p.z, p.z}, cr);
        v2f s2 = q2v + (v2f){p.w, p.w};
        v2f d2 = __builtin_elementwise_fma(m2v, cr, s2);
        if (fminf(d2.x, d2.y) <= Tmax) {  // conservative joint screen
          si[cnt * TPB + tid] = (unsigned short)loc;  // one store either way
          cnt++;
        }
      }
      if (__any(cnt >= TRIG)) compact(tbase);  // wave-synchronized
    }
    if (__any(cnt > 0)) compact(tbase);  // tile retires: resolve local idxs
  }

  // Epilogue: dump + 8-way merge for A, then B (reuse md/si).
#pragma unroll
  for (int s = 0; s < KK; ++s) {
    md[s * TPB + tid] = aA[s];
    si[s * TPB + tid] = (unsigned short)aiA[s];
  }
  __syncthreads();
  if (h == 0) {
    int pp[SPL];
    float hd[SPL];
    int hi[SPL];
#pragma unroll
    for (int j = 0; j < SPL; ++j) {
      pp[j] = 0;
      hd[j] = md[tid + j];
      hi[j] = si[tid + j];
    }
    float* dq = dout + (size_t)qidA * KK;
    float* iq = iout + (size_t)qidA * KK;
    for (int o = 0; o < KK; ++o) {
      int best = 0;
#pragma unroll
      for (int j = 1; j < SPL; ++j) {
        bool bt = (hd[j] < hd[best]) || (hd[j] == hd[best] && hi[j] < hi[best]);
        if (bt) best = j;
      }
      dq[o] = sqrtf(hd[best]);
      iq[o] = (float)hi[best];  // 0-based
      int np = pp[best] + 1;
      pp[best] = np;
      if (np < KK) {
        hd[best] = md[np * TPB + tid + best];
        hi[best] = si[np * TPB + tid + best];
      } else {
        hd[best] = 3.0e38f;
      }
    }
  }
  __syncthreads();
#pragma unroll
  for (int s = 0; s < KK; ++s) {
    md[s * TPB + tid] = aB[s];
    si[s * TPB + tid] = (unsigned short)aiB[s];
  }
  __syncthreads();
  if (h == 0) {
    int pp[SPL];
    float hd[SPL];
    int hi[SPL];
#pragma unroll
    for (int j = 0; j < SPL; ++j) {
      pp[j] = 0;
      hd[j] = md[tid + j];
      hi[j] = si[tid + j];
    }
    float* dq = dout + (size_t)qidB * KK;
    float* iq = iout + (size_t)qidB * KK;
    for (int o = 0; o < KK; ++o) {
      int best = 0;
#pragma unroll
      for (int j = 1; j < SPL; ++j) {
        bool bt = (hd[j] < hd[best]) || (hd[j] == hd[best] && hi[j] < hi[best]);
        if (bt) best = j;
      }
      dq[o] = sqrtf(hd[best]);
      iq[o] = (float)hi[best];  // 0-based
      int np = pp[best] + 1;
      pp[best] = np;
      if (np < KK) {
        hd[best] = md[np * TPB + tid + best];
        hi[best] = si[np * TPB + tid + best];
      } else {
        hd[best] = 3.0e38f;
      }
    }
  }
}

extern "C" void kernel_launch(void* const* d_in, const int* in_sizes, int n_in,
                              void* d_out, int out_size, void* d_ws, size_t ws_size,
                              hipStream_t stream) {
  const float* ref = (const float*)d_in[0];
  const float* query = (const float*)d_in[1];
  const int B = 4, C = 3;
  int N = in_sizes[0] / (B * C);
  int M = in_sizes[1] / (B * C);
  float* dout = (float*)d_out;
  float* iout = dout + (size_t)out_size / 2;  // idx half, written as float
  int totalQ = B * M;
  int blocks = totalQ / QPB;
  knn_topk_kernel<<<blocks, TPB, 0, stream>>>(ref, query, dout, iout, N, M);
}